// Round 11
// baseline (83.325 us; speedup 1.0000x reference)
//
#include <hip/hip_runtime.h>

namespace {
constexpr int NA    = 128;
constexpr int NC2   = NA * (NA - 1) / 2;         // 8128 (= 4*2032 exactly)
constexpr int BT    = 256;                       // threads per block
constexpr int NSLOT = 64 * 32;                   // 2048 group slots (4-wide j groups)
constexpr int NTAIL = 192;                       // ragged elements (j >= 4*floor(i/4))
constexpr float SCALE = 627.5095f * 0.529177f / 100.0f;  // AU2KCALMOLA/MAX_NRF

// clang ext_vectors: f4u for the (dword-aligned) atoms load, f4 for 16B ops.
typedef float f4u __attribute__((ext_vector_type(4), aligned(4)));
typedef float f4  __attribute__((ext_vector_type(4), aligned(16)));

// obuf intra-unit rotation swizzle (v6). v5's swz(w)=w+4*(w>>5) only ever
// adds multiples of 4 -> scalar writes with fixed tt stayed in the 8-bank
// coset {tt, tt+4,...} -> still 8-way conflicted. Fix: keep each aligned
// 4-word unit u at words [4u,4u+4) (so copy-phase ds_read_b128 stays 16B-
// aligned) and ROTATE within the unit by r(u) = (u>>3)&3. Scalar-write bank
// = (4u + (w+(u>>3))&3) mod 32: lanes t,t+8 differ by 1 bank; worst case
// 2-way (t vs t+32), which is free (m136). Copy un-rotates in registers.
__device__ __forceinline__ int obuf_phys(int w) {
    const int u = w >> 2;
    return (u << 2) | ((w + (u >> 3)) & 3);
}
}

// v6 (third submit; rounds 9-10 hit GPUAcquisitionTimeout — this exact
// source has never executed on hardware).
// v5 structure + (a) correct obuf bank swizzle, (b) NON-TEMPORAL wide
// aligned output stores.
// Evidence: v0/v2/v5 (three different store schemes) all total ~82us ->
// kernel pinned at ~20us (82 - 44 fill - ~18 harness gaps, gap calibrated
// from round 2 where kernel was visible) = 3.3 TB/s effective cached-store
// rate into the 100%-dirty L3 the 256MiB poison fill leaves behind. Theory:
// cached stores pay dirty-victim allocate; NT bypasses L2/L3 allocation.
// Round 2's NT regression was partial-line RMW from scalar-dword NT
// (WRITE_SIZE 88MB = 1.32x); v5's copy phase is wave-contiguous 16B-aligned
// 1KB bursts = full 64B sectors, so NT here writes exactly ~67MB.
// Predict: kernel visible in top-5, WRITE_SIZE ~67MB, LDS_BANK_CONFLICT ~0;
// dirty-L3 theory right -> kernel 12-16us, total 68-74. NT-path-slow ->
// total ~95 (revert signal; 82 is then the harness floor).
__global__ __launch_bounds__(BT, 4) void nrf_kernel(
    const float* __restrict__ coords,
    const float* __restrict__ atoms,
    float* __restrict__ out)
{
    __shared__ __align__(16) float4 c4[NA];       // AoS: ci reads + tail
    __shared__ __align__(16) float  soa[3][NA];   // SoA: cj b128 reads
    __shared__ __align__(16) float  obuf[NC2];    // rotation-swizzled staging

    const int b   = blockIdx.x;                   // one batch row per block
    const int tid = threadIdx.x;

    // Stage 1 row (384 floats) into both AoS float4 and SoA x/y/z.
    const float* cb = coords + (size_t)b * (NA * 3);
    float* c4f = reinterpret_cast<float*>(c4);
    float* sof = &soa[0][0];
    for (int k = tid; k < NA * 3; k += BT) {
        const float v = cb[k];
        const int atom = k / 3;                   // magic mul
        const int comp = k - atom * 3;
        c4f[atom * 4 + comp] = v;
        sof[comp * NA + atom] = v;
    }
    __syncthreads();

    // Main: 2048 slots, each = 4 consecutive j within one row i.
    // Chunk c (32 slots): row iA=c+1 (fA=iA/4 groups, slots s<fA) and row
    // iB=126-c (fB groups, slots s>=fA); chunk 63 = row 127. <=1 idle
    // slot/chunk. (Coverage verified on HW: v4/v5 passed with this scheme.)
    #pragma unroll
    for (int it = 0; it < NSLOT / BT; ++it) {     // 8 iterations
        const int slot = it * BT + tid;
        const int c  = slot >> 5;
        const int s  = slot & 31;
        const int iA = (c < 63) ? c + 1 : 127;
        const int fA = iA >> 2;
        const int fB = (c < 63) ? ((126 - c) >> 2) : 0;
        if (s < fA + fB) {
            const bool lo = s < fA;
            const int i  = lo ? iA : 126 - c;
            const int t  = lo ? s : s - fA;
            const int j0 = t << 2;
            const int p0 = ((i * (i - 1)) >> 1) + j0;

            f4u av = *reinterpret_cast<const f4u*>(atoms + p0);
            av *= SCALE;

            const float4 ci = c4[i];              // <=4 distinct/wave: bcast
            // lane-contiguous, conflict-free b128 (j0 = 4t, lanes t consec)
            const float4 xj = *reinterpret_cast<const float4*>(&soa[0][j0]);
            const float4 yj = *reinterpret_cast<const float4*>(&soa[1][j0]);
            const float4 zj = *reinterpret_cast<const float4*>(&soa[2][j0]);

            const float xr[4] = {xj.x, xj.y, xj.z, xj.w};
            const float yr[4] = {yj.x, yj.y, yj.z, yj.w};
            const float zr[4] = {zj.x, zj.y, zj.z, zj.w};
            #pragma unroll
            for (int tt = 0; tt < 4; ++tt) {
                const float dx = ci.x - xr[tt];
                const float dy = ci.y - yr[tt];
                const float dz = ci.z - zr[tt];
                const float d2 = dx * dx + dy * dy + dz * dz;
                // ref: 1/(sqrt d2)^2 == 1/d2 within ~2 ulp; rcp is 1 ulp
                obuf[obuf_phys(p0 + tt)] = av[tt] * __builtin_amdgcn_rcpf(d2);
            }
        }
    }

    // Tail: 192 elements with j >= 4*floor(i/4). e = 6*mq+s6 ->
    // (di,dj) in {(1,0),(2,0),(2,1),(3,0),(3,1),(3,2)}; i=4mq+di, j=4mq+dj.
    if (tid < NTAIL) {
        const int e  = tid;
        const int mq = e / 6;                     // magic mul
        const int s6 = e - 6 * mq;
        const int di = 1 + (s6 >= 1) + (s6 >= 3);
        const int dj = s6 - ((di * (di - 1)) >> 1);
        const int i  = 4 * mq + di;
        const int j  = 4 * mq + dj;
        const int p  = ((i * (i - 1)) >> 1) + j;
        const float4 ci = c4[i];
        const float4 cj = c4[j];
        const float dx = ci.x - cj.x;
        const float dy = ci.y - cj.y;
        const float dz = ci.z - cj.z;
        const float d2 = dx * dx + dy * dy + dz * dz;
        obuf[obuf_phys(p)] = atoms[p] * SCALE * __builtin_amdgcn_rcpf(d2);
    }
    __syncthreads();

    // Copy out: per lane one 16B-aligned ds_read_b128 of unit k, un-rotate
    // in registers (stored[s] holds logical[(s-r)&3], r=(k>>3)&3 -> logical
    // = rotate-left-by-r of stored), then NT dwordx4 store. Wave writes
    // 1KB contiguous 16B-aligned = full 64B sectors -> NT with no partial-
    // line RMW (round 2's failure mode), no dirty-L3 victim allocation.
    float* outb = out + (size_t)b * NC2;          // b*32512B: 16B-aligned
    for (int k = tid; k < NC2 / 4; k += BT) {     // 2032 -> 8 iters
        const int r = (k >> 3) & 3;
        f4 v = *reinterpret_cast<const f4*>(&obuf[k << 2]);
        // branchless rotate-left by r (r&2 then r&1); elementwise cndmask
        f4 v2 = __builtin_shufflevector(v, v, 2, 3, 0, 1);
        v = (r & 2) ? v2 : v;
        f4 v1 = __builtin_shufflevector(v, v, 1, 2, 3, 0);
        v = (r & 1) ? v1 : v;
        __builtin_nontemporal_store(v, reinterpret_cast<f4*>(outb + (k << 2)));
    }
}

extern "C" void kernel_launch(void* const* d_in, const int* in_sizes, int n_in,
                              void* d_out, int out_size, void* d_ws, size_t ws_size,
                              hipStream_t stream)
{
    const float* coords = (const float*)d_in[0];
    const float* atoms  = (const float*)d_in[1];
    float*       out    = (float*)d_out;
    const int batch = in_sizes[0] / (NA * 3);     // 2048
    nrf_kernel<<<batch, BT, 0, stream>>>(coords, atoms, out);
}

// Round 12
// 82.561 us; speedup vs baseline: 1.0093x; 1.0093x over previous
//
#include <hip/hip_runtime.h>

namespace {
constexpr int NA    = 128;
constexpr int NC2   = NA * (NA - 1) / 2;         // 8128 (= 4*2032 exactly)
constexpr int BT    = 256;                       // threads per block
constexpr int NSLOT = 64 * 32;                   // 2048 group slots (4-wide j groups)
constexpr int NTAIL = 192;                       // ragged elements (j >= 4*floor(i/4))
constexpr float SCALE = 627.5095f * 0.529177f / 100.0f;  // AU2KCALMOLA/MAX_NRF

// clang ext_vectors: f4u for the (dword-aligned) atoms load, f4 for 16B ops.
typedef float f4u __attribute__((ext_vector_type(4), aligned(4)));
typedef float f4  __attribute__((ext_vector_type(4), aligned(16)));

// obuf intra-unit rotation swizzle. Keep each aligned 4-word unit u at
// words [4u,4u+4) (copy-phase ds_read_b128 stays 16B-aligned), ROTATE
// within the unit by r(u)=(u>>3)&3. Scalar-write bank = (4u+(w+(u>>3))&3)
// mod 32: lanes t,t+8 differ by one bank; worst case 2-way (free, m136).
// Copy un-rotates in registers.
__device__ __forceinline__ int obuf_phys(int w) {
    const int u = w >> 2;
    return (u << 2) | ((w + (u >> 3)) & 3);
}
}

// v7 = v6 with CACHED stores restored (single variable vs v6: drop NT).
// Round-11 evidence: NT full-line = 83.3 vs cached v5 = 81.6; with round
// 2's NT-scalar (2.0 TB/s actual), the NT path is intrinsically ~2-3 TB/s
// on this chip -> cached stores strictly better. Dirty-L3 allocate theory
// dead. Four structurally different kernels span 81.6-83.3: instruction
// count /3, occupancy x2, store policy, alignment all null -> kernel is
// already at/near its ~11us write-BW floor (stores are fire-and-forget;
// drain overlaps next blocks' compute), total is harness-dominated
// (fill 44-48 + ~17-24 dispatch gaps + kernel).
// Keep the corrected rotation swizzle (strictly fewer LDS write conflicts
// than v5's arithmetically-null swz; costs nothing).
// Predict: total ~81.5 +/- 1. If so -> declare ROOFLINE next round.
__global__ __launch_bounds__(BT, 4) void nrf_kernel(
    const float* __restrict__ coords,
    const float* __restrict__ atoms,
    float* __restrict__ out)
{
    __shared__ __align__(16) float4 c4[NA];       // AoS: ci reads + tail
    __shared__ __align__(16) float  soa[3][NA];   // SoA: cj b128 reads
    __shared__ __align__(16) float  obuf[NC2];    // rotation-swizzled staging

    const int b   = blockIdx.x;                   // one batch row per block
    const int tid = threadIdx.x;

    // Stage 1 row (384 floats) into both AoS float4 and SoA x/y/z.
    const float* cb = coords + (size_t)b * (NA * 3);
    float* c4f = reinterpret_cast<float*>(c4);
    float* sof = &soa[0][0];
    for (int k = tid; k < NA * 3; k += BT) {
        const float v = cb[k];
        const int atom = k / 3;                   // magic mul
        const int comp = k - atom * 3;
        c4f[atom * 4 + comp] = v;
        sof[comp * NA + atom] = v;
    }
    __syncthreads();

    // Main: 2048 slots, each = 4 consecutive j within one row i.
    // Chunk c (32 slots): row iA=c+1 (fA=iA/4 groups, slots s<fA) and row
    // iB=126-c (fB groups, slots s>=fA); chunk 63 = row 127. <=1 idle
    // slot/chunk. (Coverage verified on HW: v4/v5/v6 passed.)
    #pragma unroll
    for (int it = 0; it < NSLOT / BT; ++it) {     // 8 iterations
        const int slot = it * BT + tid;
        const int c  = slot >> 5;
        const int s  = slot & 31;
        const int iA = (c < 63) ? c + 1 : 127;
        const int fA = iA >> 2;
        const int fB = (c < 63) ? ((126 - c) >> 2) : 0;
        if (s < fA + fB) {
            const bool lo = s < fA;
            const int i  = lo ? iA : 126 - c;
            const int t  = lo ? s : s - fA;
            const int j0 = t << 2;
            const int p0 = ((i * (i - 1)) >> 1) + j0;

            f4u av = *reinterpret_cast<const f4u*>(atoms + p0);
            av *= SCALE;

            const float4 ci = c4[i];              // <=4 distinct/wave: bcast
            // lane-contiguous, conflict-free b128 (j0 = 4t, lanes t consec)
            const float4 xj = *reinterpret_cast<const float4*>(&soa[0][j0]);
            const float4 yj = *reinterpret_cast<const float4*>(&soa[1][j0]);
            const float4 zj = *reinterpret_cast<const float4*>(&soa[2][j0]);

            const float xr[4] = {xj.x, xj.y, xj.z, xj.w};
            const float yr[4] = {yj.x, yj.y, yj.z, yj.w};
            const float zr[4] = {zj.x, zj.y, zj.z, zj.w};
            #pragma unroll
            for (int tt = 0; tt < 4; ++tt) {
                const float dx = ci.x - xr[tt];
                const float dy = ci.y - yr[tt];
                const float dz = ci.z - zr[tt];
                const float d2 = dx * dx + dy * dy + dz * dz;
                // ref: 1/(sqrt d2)^2 == 1/d2 within ~2 ulp; rcp is 1 ulp
                obuf[obuf_phys(p0 + tt)] = av[tt] * __builtin_amdgcn_rcpf(d2);
            }
        }
    }

    // Tail: 192 elements with j >= 4*floor(i/4). e = 6*mq+s6 ->
    // (di,dj) in {(1,0),(2,0),(2,1),(3,0),(3,1),(3,2)}; i=4mq+di, j=4mq+dj.
    if (tid < NTAIL) {
        const int e  = tid;
        const int mq = e / 6;                     // magic mul
        const int s6 = e - 6 * mq;
        const int di = 1 + (s6 >= 1) + (s6 >= 3);
        const int dj = s6 - ((di * (di - 1)) >> 1);
        const int i  = 4 * mq + di;
        const int j  = 4 * mq + dj;
        const int p  = ((i * (i - 1)) >> 1) + j;
        const float4 ci = c4[i];
        const float4 cj = c4[j];
        const float dx = ci.x - cj.x;
        const float dy = ci.y - cj.y;
        const float dz = ci.z - cj.z;
        const float d2 = dx * dx + dy * dy + dz * dz;
        obuf[obuf_phys(p)] = atoms[p] * SCALE * __builtin_amdgcn_rcpf(d2);
    }
    __syncthreads();

    // Copy out: per lane one 16B-aligned ds_read_b128 of unit k, un-rotate
    // in registers (stored[s] holds logical[(s-r)&3], r=(k>>3)&3 -> logical
    // = rotate-left-by-r of stored), then CACHED dwordx4 store. Wave writes
    // 1KB contiguous 16B-aligned bursts; stores are fire-and-forget, drain
    // overlaps the next blocks' compute.
    float* outb = out + (size_t)b * NC2;          // b*32512B: 16B-aligned
    for (int k = tid; k < NC2 / 4; k += BT) {     // 2032 -> 8 iters
        const int r = (k >> 3) & 3;
        f4 v = *reinterpret_cast<const f4*>(&obuf[k << 2]);
        // branchless rotate-left by r (r&2 then r&1); elementwise cndmask
        f4 v2 = __builtin_shufflevector(v, v, 2, 3, 0, 1);
        v = (r & 2) ? v2 : v;
        f4 v1 = __builtin_shufflevector(v, v, 1, 2, 3, 0);
        v = (r & 1) ? v1 : v;
        *reinterpret_cast<f4*>(outb + (k << 2)) = v;
    }
}

extern "C" void kernel_launch(void* const* d_in, const int* in_sizes, int n_in,
                              void* d_out, int out_size, void* d_ws, size_t ws_size,
                              hipStream_t stream)
{
    const float* coords = (const float*)d_in[0];
    const float* atoms  = (const float*)d_in[1];
    float*       out    = (float*)d_out;
    const int batch = in_sizes[0] / (NA * 3);     // 2048
    nrf_kernel<<<batch, BT, 0, stream>>>(coords, atoms, out);
}